// Round 2
// baseline (426.328 us; speedup 1.0000x reference)
//
#include <hip/hip_runtime.h>
#include <cstdint>

typedef unsigned short u16;
typedef __bf16 bf16x8 __attribute__((ext_vector_type(8)));
typedef float f32x4 __attribute__((ext_vector_type(4)));
typedef float f32x2 __attribute__((ext_vector_type(2)));

#define AS1 __attribute__((address_space(1)))
#define AS3 __attribute__((address_space(3)))

// ---------- exact MX quant-dequant helpers (HW fp8 path) ----------

__device__ __forceinline__ int floor_log2(float x) {
    unsigned b = __float_as_uint(x);
    if (b < 0x00800000u) {                       // subnormal (rare)
        b = __float_as_uint(x * 16777216.0f);    // * 2^24 exact
        return (int)(b >> 23) - 151;
    }
    return (int)(b >> 23) - 127;
}

__device__ __forceinline__ float exp2i(int e) {
    if (e >= -126) return __uint_as_float((unsigned)(e + 127) << 23);
    return __uint_as_float(0x00400000u >> (-127 - e));
}

__device__ __forceinline__ int shared_exp(float amax) {
    float safe = (amax == 0.0f) ? 1.0f : amax;
    int se = floor_log2(safe) - 8;
    return se < -127 ? -127 : (se > 127 ? 127 : se);
}

// qdq two values with independent scales; exact e4m3fn RNE via HW cvt
__device__ __forceinline__ void qdq2s(float v0, float v1, float i0, float i1,
                                      float s0, float s1, float& o0, float& o1) {
    float y0 = fminf(fmaxf(v0 * i0, -448.0f), 448.0f);
    float y1 = fminf(fmaxf(v1 * i1, -448.0f), 448.0f);
    int pk = __builtin_amdgcn_cvt_pk_fp8_f32(y0, y1, 0, false);
    f32x2 f = __builtin_amdgcn_cvt_pk_f32_fp8(pk, false);
    o0 = f.x * s0;
    o1 = f.y * s1;
}

__device__ __forceinline__ unsigned pack_bf16(float a, float b) {
    return (__float_as_uint(a) >> 16) | (__float_as_uint(b) & 0xffff0000u);
}

// ---------- kernel 1: row-major qdq fp32 -> bf16 (blocks = 32 consecutive) ----------
__global__ void qdq_rows(const float* __restrict__ in, u16* __restrict__ out) {
    size_t t = (size_t)blockIdx.x * 256 + threadIdx.x;
    float4 v0 = ((const float4*)in)[t * 2];
    float4 v1 = ((const float4*)in)[t * 2 + 1];
    float a = fmaxf(fmaxf(fabsf(v0.x), fabsf(v0.y)), fmaxf(fabsf(v0.z), fabsf(v0.w)));
    a = fmaxf(a, fmaxf(fmaxf(fabsf(v1.x), fabsf(v1.y)), fmaxf(fabsf(v1.z), fabsf(v1.w))));
    a = fmaxf(a, __shfl_xor(a, 1));
    a = fmaxf(a, __shfl_xor(a, 2));
    int se = shared_exp(a);
    float s = exp2i(se), inv = exp2i(-se);
    float q0, q1, q2, q3, q4, q5, q6, q7;
    qdq2s(v0.x, v0.y, inv, inv, s, s, q0, q1);
    qdq2s(v0.z, v0.w, inv, inv, s, s, q2, q3);
    qdq2s(v1.x, v1.y, inv, inv, s, s, q4, q5);
    qdq2s(v1.z, v1.w, inv, inv, s, s, q6, q7);
    uint4 o;
    o.x = pack_bf16(q0, q1);
    o.y = pack_bf16(q2, q3);
    o.z = pack_bf16(q4, q5);
    o.w = pack_bf16(q6, q7);
    ((uint4*)out)[t] = o;
}

// ---------- kernel 2: qdq + transpose fp32 [R][C] -> bf16 [C][R] ----------
__global__ void qdq_transpose(const float* __restrict__ in, u16* __restrict__ out,
                              int R, int C) {
    __shared__ u16 tile[64][70];
    int c0 = blockIdx.x * 64, r0 = blockIdx.y * 64;
    int t = threadIdx.x;
    #pragma unroll
    for (int p = 0; p < 4; ++p) {
        int lin = p * 256 + t;
        int row = lin >> 4;
        int c4  = lin & 15;
        float4 v = *(const float4*)(in + (size_t)(r0 + row) * C + c0 + c4 * 4);
        float a = fmaxf(fmaxf(fabsf(v.x), fabsf(v.y)), fmaxf(fabsf(v.z), fabsf(v.w)));
        a = fmaxf(a, __shfl_xor(a, 1));
        a = fmaxf(a, __shfl_xor(a, 2));
        a = fmaxf(a, __shfl_xor(a, 4));
        int se = shared_exp(a);
        float s = exp2i(se), inv = exp2i(-se);
        float q0, q1, q2, q3;
        qdq2s(v.x, v.y, inv, inv, s, s, q0, q1);
        qdq2s(v.z, v.w, inv, inv, s, s, q2, q3);
        tile[c4 * 4 + 0][row] = (u16)(__float_as_uint(q0) >> 16);
        tile[c4 * 4 + 1][row] = (u16)(__float_as_uint(q1) >> 16);
        tile[c4 * 4 + 2][row] = (u16)(__float_as_uint(q2) >> 16);
        tile[c4 * 4 + 3][row] = (u16)(__float_as_uint(q3) >> 16);
    }
    __syncthreads();
    #pragma unroll
    for (int p = 0; p < 4; ++p) {
        int lin = p * 256 + t;
        int n  = lin >> 4;
        int k4 = lin & 15;
        unsigned lo = *(const unsigned*)&tile[n][k4 * 4];
        unsigned hi = *(const unsigned*)&tile[n][k4 * 4 + 2];
        *(uint2*)(out + (size_t)(c0 + n) * R + r0 + k4 * 4) = make_uint2(lo, hi);
    }
}

// ---------- 256x256 8-phase GEMM core (T2+T3+T4+T5, early-issued ds_reads) ----------
// 512 threads = 8 waves (2M x 4N). BK=64, LDS 128 KiB double-buffered.
// Each tile half is [128][64] bf16; 16B chunk at (row, slot) stores global slot
// (slot ^ (row&7))  -> linear gload_lds dest + inverse-swizzled source + swizzled read.
// Wave w: A rows (w>>2)*64+0..63 in EACH A-half, B cols (w&3)*32+0..31 in EACH B-half.
// Phases per K-tile: Q00 -> Q01 -> Q11 -> Q10 (one A-half + one B-half per phase).
// Staging ledger (1 half/phase, vmcnt(6) at phases 4 & 8, never drained to 0):
//  p1: t(2i+1).B0->buf1   p2: t(2i+2).A0->buf0   p3: t(2i+2).B1->buf0
//  p4: t(2i+2).A1->buf0   p5: t(2i+2).B0->buf0   p6: t(2i+3).A0->buf1
//  p7: t(2i+3).B1->buf1   p8: t(2i+3).A1->buf1
// Fragment ds_reads are EARLY-ISSUED one phase ahead, inside the previous phase's
// MFMA window (after MID barrier+lgkmcnt, in program order after the MFMA cluster).
// Buffer-switch reads (buf1 at p4, next buf0 at p8) are issued after that phase's
// VMW+barrier, so write-before-read coverage is unchanged. Read-before-write:
// every region's reads drain at a MID lgkmcnt(0) >=1 barrier before its next stage.
__device__ __forceinline__ void gemm_core256(const u16* __restrict__ A,
                                             const u16* __restrict__ B,
                                             u16* As, u16* Bs,
                                             int m0, int n0, f32x4 acc[8][4]) {
    const int K = 4096;
    const int t = threadIdx.x;
    const int w = t >> 6, lane = t & 63;
    const int l15 = lane & 15, lq = lane >> 4, fr = l15 & 7;
    const int wmc = (w >> 2) * 64;       // M chunk within each A-half
    const int wnc = (w & 3) * 32;        // N chunk within each B-half

    // fragment ds_read element offsets within a [128][64] half (swizzled)
    int aoff[4][2], boff[2][2];
    #pragma unroll
    for (int m = 0; m < 4; ++m)
        #pragma unroll
        for (int ks = 0; ks < 2; ++ks)
            aoff[m][ks] = (wmc + m * 16 + l15) * 64 + (((ks * 4 + lq) ^ fr) * 8);
    #pragma unroll
    for (int nf = 0; nf < 2; ++nf)
        #pragma unroll
        for (int ks = 0; ks < 2; ++ks)
            boff[nf][ks] = (wnc + nf * 16 + l15) * 64 + (((ks * 4 + lq) ^ fr) * 8);

    // staging: chunk ch (0..1023) = LDS 16B slot; holds global (row=ch>>3, slot=(ch&7)^(row&7))
    const int ch0 = t, ch1 = 512 + t;
    const int r0 = ch0 >> 3, r1 = ch1 >> 3;
    const size_t soff0 = (size_t)r0 * K + ((ch0 & 7) ^ (r0 & 7)) * 8;
    const size_t soff1 = (size_t)r1 * K + ((ch1 & 7) ^ (r1 & 7)) * 8;
    const int doff0 = ch0 * 8, doff1 = ch1 * 8;

    const u16* pA0 = A + (size_t)m0 * K;
    const u16* pA1 = A + (size_t)(m0 + 128) * K;
    const u16* pB0 = B + (size_t)n0 * K;
    const u16* pB1 = B + (size_t)(n0 + 128) * K;

    u16* A0b0 = As;            u16* A1b0 = As + 8192;
    u16* A0b1 = As + 16384;    u16* A1b1 = As + 24576;
    u16* B0b0 = Bs;            u16* B1b0 = Bs + 8192;
    u16* B0b1 = Bs + 16384;    u16* B1b1 = Bs + 24576;

#define STAGE(dst, src, kt) do {                                                          \
    __builtin_amdgcn_global_load_lds((const AS1 unsigned*)((src) + soff0 + (size_t)(kt) * 64), \
                                     (AS3 unsigned*)&(dst)[doff0], 16, 0, 0);             \
    __builtin_amdgcn_global_load_lds((const AS1 unsigned*)((src) + soff1 + (size_t)(kt) * 64), \
                                     (AS3 unsigned*)&(dst)[doff1], 16, 0, 0); } while (0)

#define LOAD_A(base) do {                                                                 \
    _Pragma("unroll") for (int m = 0; m < 4; ++m)                                         \
    _Pragma("unroll") for (int ks = 0; ks < 2; ++ks)                                      \
        af[m][ks] = *(const bf16x8*)&(base)[aoff[m][ks]]; } while (0)

#define LOAD_B(dstf, base) do {                                                           \
    _Pragma("unroll") for (int nf = 0; nf < 2; ++nf)                                      \
    _Pragma("unroll") for (int ks = 0; ks < 2; ++ks)                                      \
        dstf[nf][ks] = *(const bf16x8*)&(base)[boff[nf][ks]]; } while (0)

// ks outermost: 8 independent MFMAs separate the two dependent ks-steps per acc
#define MFMA_Q(mb, nb, BF) do {                                                           \
    _Pragma("unroll") for (int ks = 0; ks < 2; ++ks)                                      \
    _Pragma("unroll") for (int m = 0; m < 4; ++m)                                         \
    _Pragma("unroll") for (int nf = 0; nf < 2; ++nf)                                      \
        acc[(mb) + m][(nb) + nf] = __builtin_amdgcn_mfma_f32_16x16x32_bf16(               \
            af[m][ks], BF[nf][ks], acc[(mb) + m][(nb) + nf], 0, 0, 0); } while (0)

#define MID() do { __builtin_amdgcn_s_barrier();                                          \
    asm volatile("s_waitcnt lgkmcnt(0)" ::: "memory");                                    \
    __builtin_amdgcn_s_setprio(1); } while (0)
#define END() do { __builtin_amdgcn_s_setprio(0); __builtin_amdgcn_s_barrier(); } while (0)
#define VMW() asm volatile("s_waitcnt vmcnt(6)" ::: "memory")

    #pragma unroll
    for (int mi = 0; mi < 8; ++mi)
        #pragma unroll
        for (int ni = 0; ni < 4; ++ni)
            acc[mi][ni] = (f32x4)0.f;

    bf16x8 af[4][2], bf0[2][2], bf1[2][2];

    // prologue: tile0 {A0,B1,A1,B0}->buf0, tile1 {A0,B1,A1}->buf1; keep newest 3 in flight
    STAGE(A0b0, pA0, 0);
    STAGE(B1b0, pB1, 0);
    STAGE(A1b0, pA1, 0);
    STAGE(B0b0, pB0, 0);
    STAGE(A0b1, pA0, 1);
    STAGE(B1b1, pB1, 1);
    STAGE(A1b1, pA1, 1);
    VMW();
    __builtin_amdgcn_s_barrier();
    LOAD_A(A0b0); LOAD_B(bf0, B0b0);   // phase-1 fragments (exposed once)

    #pragma unroll 1
    for (int i = 0; i < 32; ++i) {
        const int t1 = (2 * i + 1) & 63, t2 = (2 * i + 2) & 63, t3 = (2 * i + 3) & 63;
        // phase 1: Q(0,0) of tile 2i (buf0); early-read B1b0 for p2
        STAGE(B0b1, pB0, t1);
        MID(); MFMA_Q(0, 0, bf0); LOAD_B(bf1, B1b0); END();
        // phase 2: Q(0,1); early-read A1b0 for p3
        STAGE(A0b0, pA0, t2);
        MID(); MFMA_Q(0, 2, bf1); LOAD_A(A1b0); END();
        // phase 3: Q(1,1); p4 reuses af+bf0 -> no reads
        STAGE(B1b0, pB1, t2);
        MID(); MFMA_Q(4, 2, bf1); END();
        // phase 4: Q(1,0); buf-switch: after VMW+barrier, early-read buf1 for p5
        STAGE(A1b0, pA1, t2);
        VMW();
        MID(); MFMA_Q(4, 0, bf0); LOAD_A(A0b1); LOAD_B(bf0, B0b1); END();
        // phase 5: Q(0,0) of tile 2i+1 (buf1); early-read B1b1 for p6
        STAGE(B0b0, pB0, t2);
        MID(); MFMA_Q(0, 0, bf0); LOAD_B(bf1, B1b1); END();
        // phase 6: Q(0,1); early-read A1b1 for p7
        STAGE(A0b1, pA0, t3);
        MID(); MFMA_Q(0, 2, bf1); LOAD_A(A1b1); END();
        // phase 7: Q(1,1)
        STAGE(B1b1, pB1, t3);
        MID(); MFMA_Q(4, 2, bf1); END();
        // phase 8: Q(1,0); buf-switch: early-read next buf0 for next p1
        STAGE(A1b1, pA1, t3);
        VMW();
        MID(); MFMA_Q(4, 0, bf0); LOAD_A(A0b0); LOAD_B(bf0, B0b0); END();
    }
#undef STAGE
#undef LOAD_A
#undef LOAD_B
#undef MFMA_Q
#undef MID
#undef END
#undef VMW
}

// bijective XCD swizzle for a 16x16 block grid (nwg=256, 256%8==0):
// each XCD gets 32 consecutive wgs = 2 full M-bands -> A-panel L2 reuse.
__device__ __forceinline__ void swizzle_bid(int& m0, int& n0) {
    int id = blockIdx.x;
    int wg = (id & 7) * 32 + (id >> 3);
    m0 = (wg >> 4) * 256;
    n0 = (wg & 15) * 256;
}

// GEMM1: C = A*B^T, output re-quantized to MX bf16 (blocks = 32 cols) in-register
__global__ __launch_bounds__(512, 2) void gemm1_fused(const u16* __restrict__ A,
                                                      const u16* __restrict__ B,
                                                      u16* __restrict__ Cq) {
    const int N = 4096;
    extern __shared__ __align__(16) char smem[];
    u16* As = (u16*)smem;
    u16* Bs = (u16*)(smem + 65536);
    int m0, n0;
    swizzle_bid(m0, n0);
    f32x4 acc[8][4];
    gemm_core256(A, B, As, Bs, m0, n0, acc);

    const int t = threadIdx.x, w = t >> 6, lane = t & 63;
    const int l15 = lane & 15, lq = lane >> 4;
    const int wmc = (w >> 2) * 64, wnc = (w & 3) * 32;

    // C/D layout (16x16x32): col = lane&15, row = (lane>>4)*4 + reg
    // MX block = 32 consecutive output cols = frag pair (2*nq, 2*nq+1)
    #pragma unroll
    for (int mi = 0; mi < 8; ++mi) {
        const int gr_base = m0 + (mi >> 2) * 128 + wmc + (mi & 3) * 16 + lq * 4;
        #pragma unroll
        for (int nq = 0; nq < 2; ++nq) {
            const int gc = n0 + nq * 128 + wnc + l15;
            float sc[4], iv[4];
            #pragma unroll
            for (int reg = 0; reg < 4; ++reg) {
                float a = fmaxf(fabsf(acc[mi][2 * nq][reg]), fabsf(acc[mi][2 * nq + 1][reg]));
                a = fmaxf(a, __shfl_xor(a, 1));
                a = fmaxf(a, __shfl_xor(a, 2));
                a = fmaxf(a, __shfl_xor(a, 4));
                a = fmaxf(a, __shfl_xor(a, 8));
                int se = shared_exp(a);
                sc[reg] = exp2i(se);
                iv[reg] = exp2i(-se);
            }
            #pragma unroll
            for (int reg = 0; reg < 4; ++reg) {
                float q0, q1;
                qdq2s(acc[mi][2 * nq][reg], acc[mi][2 * nq + 1][reg],
                      iv[reg], iv[reg], sc[reg], sc[reg], q0, q1);
                Cq[(size_t)(gr_base + reg) * N + gc]      = (u16)(__float_as_uint(q0) >> 16);
                Cq[(size_t)(gr_base + reg) * N + gc + 16] = (u16)(__float_as_uint(q1) >> 16);
            }
        }
    }
}

// GEMM2: C = A*B^T, plain fp32 output
__global__ __launch_bounds__(512, 2) void gemm2(const u16* __restrict__ A,
                                                const u16* __restrict__ B,
                                                float* __restrict__ C) {
    const int N = 4096;
    extern __shared__ __align__(16) char smem[];
    u16* As = (u16*)smem;
    u16* Bs = (u16*)(smem + 65536);
    int m0, n0;
    swizzle_bid(m0, n0);
    f32x4 acc[8][4];
    gemm_core256(A, B, As, Bs, m0, n0, acc);

    const int t = threadIdx.x, w = t >> 6, lane = t & 63;
    const int l15 = lane & 15, lq = lane >> 4;
    const int wmc = (w >> 2) * 64, wnc = (w & 3) * 32;

    #pragma unroll
    for (int mi = 0; mi < 8; ++mi) {
        const int gr_base = m0 + (mi >> 2) * 128 + wmc + (mi & 3) * 16 + lq * 4;
        #pragma unroll
        for (int ni = 0; ni < 4; ++ni) {
            const int gc = n0 + (ni >> 1) * 128 + wnc + (ni & 1) * 16 + l15;
            #pragma unroll
            for (int reg = 0; reg < 4; ++reg)
                C[(size_t)(gr_base + reg) * N + gc] = acc[mi][ni][reg];
        }
    }
}

// ---------- launch ----------
extern "C" void kernel_launch(void* const* d_in, const int* in_sizes, int n_in,
                              void* d_out, int out_size, void* d_ws, size_t ws_size,
                              hipStream_t stream) {
    const float* x  = (const float*)d_in[0];
    const float* m1 = (const float*)d_in[1];
    const float* m2 = (const float*)d_in[2];
    float* out = (float*)d_out;

    const int M = 4096, K = 4096, N = 4096;
    const size_t MB = 1024 * 1024;
    char* ws = (char*)d_ws;
    u16* xq   = (u16*)(ws + 0 * MB);    // 32 MB  qdq(x) bf16 [M][K]
    u16* m1qT = (u16*)(ws + 32 * MB);   // 32 MB  qdq(mat1)^T bf16 [K][K]
    u16* m2qT = (u16*)(ws + 64 * MB);   // 32 MB  qdq(mat2)^T bf16 [N][K]
    u16* xrq  = (u16*)(ws + 96 * MB);   // 32 MB  qdq(x@m1) bf16 [M][K]

    static bool s_init = false;
    if (!s_init) {
        hipFuncSetAttribute((const void*)gemm1_fused,
                            hipFuncAttributeMaxDynamicSharedMemorySize, 131072);
        hipFuncSetAttribute((const void*)gemm2,
                            hipFuncAttributeMaxDynamicSharedMemorySize, 131072);
        s_init = true;
    }

    dim3 b(256);
    qdq_rows<<<dim3((M * K) / 2048), b, 0, stream>>>(x, xq);
    qdq_transpose<<<dim3(K / 64, K / 64), b, 0, stream>>>(m1, m1qT, K, K);
    qdq_transpose<<<dim3(N / 64, K / 64), b, 0, stream>>>(m2, m2qT, K, N);
    gemm1_fused<<<dim3(256), dim3(512), 131072, stream>>>(xq, m1qT, xrq);
    gemm2<<<dim3(256), dim3(512), 131072, stream>>>(xrq, m2qT, out);
}

// Round 3
// 409.722 us; speedup vs baseline: 1.0405x; 1.0405x over previous
//
#include <hip/hip_runtime.h>
#include <cstdint>

typedef unsigned short u16;
typedef __bf16 bf16x8 __attribute__((ext_vector_type(8)));
typedef float f32x4 __attribute__((ext_vector_type(4)));
typedef float f32x2 __attribute__((ext_vector_type(2)));

#define AS1 __attribute__((address_space(1)))
#define AS3 __attribute__((address_space(3)))

// ---------- exact MX quant-dequant helpers (HW fp8 path) ----------

__device__ __forceinline__ int floor_log2(float x) {
    unsigned b = __float_as_uint(x);
    if (b < 0x00800000u) {                       // subnormal (rare)
        b = __float_as_uint(x * 16777216.0f);    // * 2^24 exact
        return (int)(b >> 23) - 151;
    }
    return (int)(b >> 23) - 127;
}

__device__ __forceinline__ float exp2i(int e) {
    if (e >= -126) return __uint_as_float((unsigned)(e + 127) << 23);
    return __uint_as_float(0x00400000u >> (-127 - e));
}

__device__ __forceinline__ int shared_exp(float amax) {
    float safe = (amax == 0.0f) ? 1.0f : amax;
    int se = floor_log2(safe) - 8;
    return se < -127 ? -127 : (se > 127 ? 127 : se);
}

// qdq two values with independent scales; exact e4m3fn RNE via HW cvt
__device__ __forceinline__ void qdq2s(float v0, float v1, float i0, float i1,
                                      float s0, float s1, float& o0, float& o1) {
    float y0 = fminf(fmaxf(v0 * i0, -448.0f), 448.0f);
    float y1 = fminf(fmaxf(v1 * i1, -448.0f), 448.0f);
    int pk = __builtin_amdgcn_cvt_pk_fp8_f32(y0, y1, 0, false);
    f32x2 f = __builtin_amdgcn_cvt_pk_f32_fp8(pk, false);
    o0 = f.x * s0;
    o1 = f.y * s1;
}

__device__ __forceinline__ unsigned pack_bf16(float a, float b) {
    return (__float_as_uint(a) >> 16) | (__float_as_uint(b) & 0xffff0000u);
}

// ---------- fused qdq kernel: one launch for all three preprocessing jobs ----------
// blocks [0, 8192)        : row-major qdq of x          -> xq   (bf16 [M][K])
// blocks [8192, 12288)    : qdq + transpose of mat1     -> m1qT (bf16 [K][K])
// blocks [12288, 16384)   : qdq + transpose of mat2     -> m2qT (bf16 [N][K])

__device__ __forceinline__ void qdq_rows_body(const float* __restrict__ in,
                                              u16* __restrict__ out, int bid) {
    size_t t = (size_t)bid * 256 + threadIdx.x;
    float4 v0 = ((const float4*)in)[t * 2];
    float4 v1 = ((const float4*)in)[t * 2 + 1];
    float a = fmaxf(fmaxf(fabsf(v0.x), fabsf(v0.y)), fmaxf(fabsf(v0.z), fabsf(v0.w)));
    a = fmaxf(a, fmaxf(fmaxf(fabsf(v1.x), fabsf(v1.y)), fmaxf(fabsf(v1.z), fabsf(v1.w))));
    a = fmaxf(a, __shfl_xor(a, 1));
    a = fmaxf(a, __shfl_xor(a, 2));
    int se = shared_exp(a);
    float s = exp2i(se), inv = exp2i(-se);
    float q0, q1, q2, q3, q4, q5, q6, q7;
    qdq2s(v0.x, v0.y, inv, inv, s, s, q0, q1);
    qdq2s(v0.z, v0.w, inv, inv, s, s, q2, q3);
    qdq2s(v1.x, v1.y, inv, inv, s, s, q4, q5);
    qdq2s(v1.z, v1.w, inv, inv, s, s, q6, q7);
    uint4 o;
    o.x = pack_bf16(q0, q1);
    o.y = pack_bf16(q2, q3);
    o.z = pack_bf16(q4, q5);
    o.w = pack_bf16(q6, q7);
    ((uint4*)out)[t] = o;
}

__device__ __forceinline__ void qdq_transpose_body(const float* __restrict__ in,
                                                   u16* __restrict__ out,
                                                   int bx, int by,
                                                   u16 (*tile)[70]) {
    const int R = 4096, C = 4096;
    int c0 = bx * 64, r0 = by * 64;
    int t = threadIdx.x;
    #pragma unroll
    for (int p = 0; p < 4; ++p) {
        int lin = p * 256 + t;
        int row = lin >> 4;
        int c4  = lin & 15;
        float4 v = *(const float4*)(in + (size_t)(r0 + row) * C + c0 + c4 * 4);
        float a = fmaxf(fmaxf(fabsf(v.x), fabsf(v.y)), fmaxf(fabsf(v.z), fabsf(v.w)));
        a = fmaxf(a, __shfl_xor(a, 1));
        a = fmaxf(a, __shfl_xor(a, 2));
        a = fmaxf(a, __shfl_xor(a, 4));
        int se = shared_exp(a);
        float s = exp2i(se), inv = exp2i(-se);
        float q0, q1, q2, q3;
        qdq2s(v.x, v.y, inv, inv, s, s, q0, q1);
        qdq2s(v.z, v.w, inv, inv, s, s, q2, q3);
        tile[c4 * 4 + 0][row] = (u16)(__float_as_uint(q0) >> 16);
        tile[c4 * 4 + 1][row] = (u16)(__float_as_uint(q1) >> 16);
        tile[c4 * 4 + 2][row] = (u16)(__float_as_uint(q2) >> 16);
        tile[c4 * 4 + 3][row] = (u16)(__float_as_uint(q3) >> 16);
    }
    __syncthreads();
    #pragma unroll
    for (int p = 0; p < 4; ++p) {
        int lin = p * 256 + t;
        int n  = lin >> 4;
        int k4 = lin & 15;
        unsigned lo = *(const unsigned*)&tile[n][k4 * 4];
        unsigned hi = *(const unsigned*)&tile[n][k4 * 4 + 2];
        *(uint2*)(out + (size_t)(c0 + n) * R + r0 + k4 * 4) = make_uint2(lo, hi);
    }
}

__global__ void qdq_all(const float* __restrict__ x,  u16* __restrict__ xq,
                        const float* __restrict__ m1, u16* __restrict__ m1qT,
                        const float* __restrict__ m2, u16* __restrict__ m2qT) {
    __shared__ u16 tile[64][70];
    int bid = blockIdx.x;
    if (bid < 8192) {
        qdq_rows_body(x, xq, bid);
    } else if (bid < 12288) {
        int j = bid - 8192;
        qdq_transpose_body(m1, m1qT, j & 63, j >> 6, tile);
    } else {
        int j = bid - 12288;
        qdq_transpose_body(m2, m2qT, j & 63, j >> 6, tile);
    }
}

// ---------- 256x256 8-phase GEMM core (T2+T3+T4+T5, early-issued ds_reads) ----------
// 512 threads = 8 waves (2M x 4N). BK=64, LDS 128 KiB double-buffered.
// Each tile half is [128][64] bf16; 16B chunk at (row, slot) stores global slot
// (slot ^ (row&7))  -> linear gload_lds dest + inverse-swizzled source + swizzled read.
// Read conflict check: bank-group = slot&7 = (ks*4+lq)^(row&7); for the 64 lanes each
// of the 8 groups gets exactly 8 lanes -> balanced minimum-time access, 0 conflicts.
// Phases per K-tile: Q00 -> Q01 -> Q11 -> Q10 (one A-half + one B-half per phase).
// Staging ledger (1 half/phase, vmcnt(6) at phases 4 & 8, never drained to 0):
//  p1: t(2i+1).B0->buf1   p2: t(2i+2).A0->buf0   p3: t(2i+2).B1->buf0
//  p4: t(2i+2).A1->buf0   p5: t(2i+2).B0->buf0   p6: t(2i+3).A0->buf1
//  p7: t(2i+3).B1->buf1   p8: t(2i+3).A1->buf1
// Fragment ds_reads are EARLY-ISSUED one phase ahead, inside the previous phase's
// MFMA window. NO explicit lgkmcnt(0) drain: the compiler inserts fine-grained
// lgkmcnt(N) before each consuming MFMA. Cross-wave safety (consumption sealing):
// every early-read's data is consumed by MFMAs BEFORE that phase's END barrier, and
// every region's re-stage is issued AFTER that END barrier (all 8 pairs verified).
// Zero-instruction "" memory clobbers around barriers keep compiler code motion
// from moving LDS/staging ops across barriers (raw s_barrier is not a fence).
__device__ __forceinline__ void gemm_core256(const u16* __restrict__ A,
                                             const u16* __restrict__ B,
                                             u16* As, u16* Bs,
                                             int m0, int n0, f32x4 acc[8][4]) {
    const int K = 4096;
    const int t = threadIdx.x;
    const int w = t >> 6, lane = t & 63;
    const int l15 = lane & 15, lq = lane >> 4, fr = l15 & 7;
    const int wmc = (w >> 2) * 64;       // M chunk within each A-half
    const int wnc = (w & 3) * 32;        // N chunk within each B-half

    // fragment ds_read element offsets within a [128][64] half (swizzled)
    int aoff[4][2], boff[2][2];
    #pragma unroll
    for (int m = 0; m < 4; ++m)
        #pragma unroll
        for (int ks = 0; ks < 2; ++ks)
            aoff[m][ks] = (wmc + m * 16 + l15) * 64 + (((ks * 4 + lq) ^ fr) * 8);
    #pragma unroll
    for (int nf = 0; nf < 2; ++nf)
        #pragma unroll
        for (int ks = 0; ks < 2; ++ks)
            boff[nf][ks] = (wnc + nf * 16 + l15) * 64 + (((ks * 4 + lq) ^ fr) * 8);

    // staging: chunk ch (0..1023) = LDS 16B slot; holds global (row=ch>>3, slot=(ch&7)^(row&7))
    const int ch0 = t, ch1 = 512 + t;
    const int r0 = ch0 >> 3, r1 = ch1 >> 3;
    const size_t soff0 = (size_t)r0 * K + ((ch0 & 7) ^ (r0 & 7)) * 8;
    const size_t soff1 = (size_t)r1 * K + ((ch1 & 7) ^ (r1 & 7)) * 8;
    const int doff0 = ch0 * 8, doff1 = ch1 * 8;

    const u16* pA0 = A + (size_t)m0 * K;
    const u16* pA1 = A + (size_t)(m0 + 128) * K;
    const u16* pB0 = B + (size_t)n0 * K;
    const u16* pB1 = B + (size_t)(n0 + 128) * K;

    u16* A0b0 = As;            u16* A1b0 = As + 8192;
    u16* A0b1 = As + 16384;    u16* A1b1 = As + 24576;
    u16* B0b0 = Bs;            u16* B1b0 = Bs + 8192;
    u16* B0b1 = Bs + 16384;    u16* B1b1 = Bs + 24576;

#define STAGE(dst, src, kt) do {                                                          \
    __builtin_amdgcn_global_load_lds((const AS1 unsigned*)((src) + soff0 + (size_t)(kt) * 64), \
                                     (AS3 unsigned*)&(dst)[doff0], 16, 0, 0);             \
    __builtin_amdgcn_global_load_lds((const AS1 unsigned*)((src) + soff1 + (size_t)(kt) * 64), \
                                     (AS3 unsigned*)&(dst)[doff1], 16, 0, 0); } while (0)

#define LOAD_A(base) do {                                                                 \
    _Pragma("unroll") for (int m = 0; m < 4; ++m)                                         \
    _Pragma("unroll") for (int ks = 0; ks < 2; ++ks)                                      \
        af[m][ks] = *(const bf16x8*)&(base)[aoff[m][ks]]; } while (0)

#define LOAD_B(dstf, base) do {                                                           \
    _Pragma("unroll") for (int nf = 0; nf < 2; ++nf)                                      \
    _Pragma("unroll") for (int ks = 0; ks < 2; ++ks)                                      \
        dstf[nf][ks] = *(const bf16x8*)&(base)[boff[nf][ks]]; } while (0)

// ks outermost: 8 independent MFMAs separate the two dependent ks-steps per acc
#define MFMA_Q(mb, nb, BF) do {                                                           \
    _Pragma("unroll") for (int ks = 0; ks < 2; ++ks)                                      \
    _Pragma("unroll") for (int m = 0; m < 4; ++m)                                         \
    _Pragma("unroll") for (int nf = 0; nf < 2; ++nf)                                      \
        acc[(mb) + m][(nb) + nf] = __builtin_amdgcn_mfma_f32_16x16x32_bf16(               \
            af[m][ks], BF[nf][ks], acc[(mb) + m][(nb) + nf], 0, 0, 0); } while (0)

#define FENCE() asm volatile("" ::: "memory")
#define MID() do { FENCE(); __builtin_amdgcn_s_barrier(); FENCE();                        \
    __builtin_amdgcn_s_setprio(1); } while (0)
#define END() do { __builtin_amdgcn_s_setprio(0); FENCE();                                \
    __builtin_amdgcn_s_barrier(); FENCE(); } while (0)
#define VMW() asm volatile("s_waitcnt vmcnt(6)" ::: "memory")

    #pragma unroll
    for (int mi = 0; mi < 8; ++mi)
        #pragma unroll
        for (int ni = 0; ni < 4; ++ni)
            acc[mi][ni] = (f32x4)0.f;

    bf16x8 af[4][2], bf0[2][2], bf1[2][2];

    // prologue: tile0 {A0,B1,A1,B0}->buf0, tile1 {A0,B1,A1}->buf1; keep newest 3 in flight
    STAGE(A0b0, pA0, 0);
    STAGE(B1b0, pB1, 0);
    STAGE(A1b0, pA1, 0);
    STAGE(B0b0, pB0, 0);
    STAGE(A0b1, pA0, 1);
    STAGE(B1b1, pB1, 1);
    STAGE(A1b1, pA1, 1);
    VMW();
    __builtin_amdgcn_s_barrier();
    FENCE();
    LOAD_A(A0b0); LOAD_B(bf0, B0b0);   // phase-1 fragments (exposed once)

    #pragma unroll 1
    for (int i = 0; i < 32; ++i) {
        const int t1 = (2 * i + 1) & 63, t2 = (2 * i + 2) & 63, t3 = (2 * i + 3) & 63;
        // phase 1: Q(0,0) of tile 2i (buf0); early-read B1b0 for p2
        STAGE(B0b1, pB0, t1);
        MID(); MFMA_Q(0, 0, bf0); LOAD_B(bf1, B1b0); END();
        // phase 2: Q(0,1); early-read A1b0 for p3
        STAGE(A0b0, pA0, t2);
        MID(); MFMA_Q(0, 2, bf1); LOAD_A(A1b0); END();
        // phase 3: Q(1,1); p4 reuses af+bf0 -> no reads
        STAGE(B1b0, pB1, t2);
        MID(); MFMA_Q(4, 2, bf1); END();
        // phase 4: Q(1,0); buf-switch: after VMW+barrier, early-read buf1 for p5
        STAGE(A1b0, pA1, t2);
        VMW();
        MID(); MFMA_Q(4, 0, bf0); LOAD_A(A0b1); LOAD_B(bf0, B0b1); END();
        // phase 5: Q(0,0) of tile 2i+1 (buf1); early-read B1b1 for p6
        STAGE(B0b0, pB0, t2);
        MID(); MFMA_Q(0, 0, bf0); LOAD_B(bf1, B1b1); END();
        // phase 6: Q(0,1); early-read A1b1 for p7
        STAGE(A0b1, pA0, t3);
        MID(); MFMA_Q(0, 2, bf1); LOAD_A(A1b1); END();
        // phase 7: Q(1,1)
        STAGE(B1b1, pB1, t3);
        MID(); MFMA_Q(4, 2, bf1); END();
        // phase 8: Q(1,0); buf-switch: early-read next buf0 for next p1
        STAGE(A1b1, pA1, t3);
        VMW();
        MID(); MFMA_Q(4, 0, bf0); LOAD_A(A0b0); LOAD_B(bf0, B0b0); END();
    }
#undef STAGE
#undef LOAD_A
#undef LOAD_B
#undef MFMA_Q
#undef FENCE
#undef MID
#undef END
#undef VMW
}

// bijective XCD swizzle for a 16x16 block grid (nwg=256, 256%8==0):
// each XCD gets 32 consecutive wgs = 2 full M-bands -> A-panel L2 reuse.
__device__ __forceinline__ void swizzle_bid(int& m0, int& n0) {
    int id = blockIdx.x;
    int wg = (id & 7) * 32 + (id >> 3);
    m0 = (wg >> 4) * 256;
    n0 = (wg & 15) * 256;
}

// GEMM1: C = A*B^T, output re-quantized to MX bf16 (blocks = 32 cols) in-register
__global__ __launch_bounds__(512, 2) void gemm1_fused(const u16* __restrict__ A,
                                                      const u16* __restrict__ B,
                                                      u16* __restrict__ Cq) {
    const int N = 4096;
    extern __shared__ __align__(16) char smem[];
    u16* As = (u16*)smem;
    u16* Bs = (u16*)(smem + 65536);
    int m0, n0;
    swizzle_bid(m0, n0);
    f32x4 acc[8][4];
    gemm_core256(A, B, As, Bs, m0, n0, acc);

    const int t = threadIdx.x, w = t >> 6, lane = t & 63;
    const int l15 = lane & 15, lq = lane >> 4;
    const int wmc = (w >> 2) * 64, wnc = (w & 3) * 32;

    // C/D layout (16x16x32): col = lane&15, row = (lane>>4)*4 + reg
    // MX block = 32 consecutive output cols = frag pair (2*nq, 2*nq+1)
    #pragma unroll
    for (int mi = 0; mi < 8; ++mi) {
        const int gr_base = m0 + (mi >> 2) * 128 + wmc + (mi & 3) * 16 + lq * 4;
        #pragma unroll
        for (int nq = 0; nq < 2; ++nq) {
            const int gc = n0 + nq * 128 + wnc + l15;
            float sc[4], iv[4];
            #pragma unroll
            for (int reg = 0; reg < 4; ++reg) {
                float a = fmaxf(fabsf(acc[mi][2 * nq][reg]), fabsf(acc[mi][2 * nq + 1][reg]));
                a = fmaxf(a, __shfl_xor(a, 1));
                a = fmaxf(a, __shfl_xor(a, 2));
                a = fmaxf(a, __shfl_xor(a, 4));
                a = fmaxf(a, __shfl_xor(a, 8));
                int se = shared_exp(a);
                sc[reg] = exp2i(se);
                iv[reg] = exp2i(-se);
            }
            #pragma unroll
            for (int reg = 0; reg < 4; ++reg) {
                float q0, q1;
                qdq2s(acc[mi][2 * nq][reg], acc[mi][2 * nq + 1][reg],
                      iv[reg], iv[reg], sc[reg], sc[reg], q0, q1);
                Cq[(size_t)(gr_base + reg) * N + gc]      = (u16)(__float_as_uint(q0) >> 16);
                Cq[(size_t)(gr_base + reg) * N + gc + 16] = (u16)(__float_as_uint(q1) >> 16);
            }
        }
    }
}

// GEMM2: C = A*B^T, plain fp32 output
__global__ __launch_bounds__(512, 2) void gemm2(const u16* __restrict__ A,
                                                const u16* __restrict__ B,
                                                float* __restrict__ C) {
    const int N = 4096;
    extern __shared__ __align__(16) char smem[];
    u16* As = (u16*)smem;
    u16* Bs = (u16*)(smem + 65536);
    int m0, n0;
    swizzle_bid(m0, n0);
    f32x4 acc[8][4];
    gemm_core256(A, B, As, Bs, m0, n0, acc);

    const int t = threadIdx.x, w = t >> 6, lane = t & 63;
    const int l15 = lane & 15, lq = lane >> 4;
    const int wmc = (w >> 2) * 64, wnc = (w & 3) * 32;

    #pragma unroll
    for (int mi = 0; mi < 8; ++mi) {
        const int gr_base = m0 + (mi >> 2) * 128 + wmc + (mi & 3) * 16 + lq * 4;
        #pragma unroll
        for (int ni = 0; ni < 4; ++ni) {
            const int gc = n0 + (ni >> 1) * 128 + wnc + (ni & 1) * 16 + l15;
            #pragma unroll
            for (int reg = 0; reg < 4; ++reg)
                C[(size_t)(gr_base + reg) * N + gc] = acc[mi][ni][reg];
        }
    }
}

// ---------- launch ----------
extern "C" void kernel_launch(void* const* d_in, const int* in_sizes, int n_in,
                              void* d_out, int out_size, void* d_ws, size_t ws_size,
                              hipStream_t stream) {
    const float* x  = (const float*)d_in[0];
    const float* m1 = (const float*)d_in[1];
    const float* m2 = (const float*)d_in[2];
    float* out = (float*)d_out;

    const size_t MB = 1024 * 1024;
    char* ws = (char*)d_ws;
    u16* xq   = (u16*)(ws + 0 * MB);    // 32 MB  qdq(x) bf16 [M][K]
    u16* m1qT = (u16*)(ws + 32 * MB);   // 32 MB  qdq(mat1)^T bf16 [K][K]
    u16* m2qT = (u16*)(ws + 64 * MB);   // 32 MB  qdq(mat2)^T bf16 [N][K]
    u16* xrq  = (u16*)(ws + 96 * MB);   // 32 MB  qdq(x@m1) bf16 [M][K]

    static bool s_init = false;
    if (!s_init) {
        hipFuncSetAttribute((const void*)gemm1_fused,
                            hipFuncAttributeMaxDynamicSharedMemorySize, 131072);
        hipFuncSetAttribute((const void*)gemm2,
                            hipFuncAttributeMaxDynamicSharedMemorySize, 131072);
        s_init = true;
    }

    qdq_all<<<dim3(16384), dim3(256), 0, stream>>>(x, xq, m1, m1qT, m2, m2qT);
    gemm1_fused<<<dim3(256), dim3(512), 131072, stream>>>(xq, m1qT, xrq);
    gemm2<<<dim3(256), dim3(512), 131072, stream>>>(xrq, m2qT, out);
}